// Round 3
// baseline (1332.943 us; speedup 1.0000x reference)
//
#include <hip/hip_runtime.h>
#include <math.h>

#define NN 100000
#define NE 1600000

// ---------- CSR build ----------
__global__ void count_k(const int* __restrict__ dst, int* __restrict__ cnt) {
    int e = blockIdx.x * blockDim.x + threadIdx.x;
    if (e < NE) atomicAdd(&cnt[dst[e]], 1);
}

// single-block exclusive scan of cnt (in cursor) -> row_ptr; cursor <- row_ptr copy
__global__ void scan_k(int* __restrict__ cnt_cursor, int* __restrict__ row_ptr) {
    __shared__ int buf[1024];
    __shared__ int carry;
    int tid = threadIdx.x;
    if (tid == 0) carry = 0;
    __syncthreads();
    for (int base = 0; base < NN; base += 1024) {
        int i = base + tid;
        int v = (i < NN) ? cnt_cursor[i] : 0;
        buf[tid] = v;
        __syncthreads();
        for (int off = 1; off < 1024; off <<= 1) {
            int t = (tid >= off) ? buf[tid - off] : 0;
            __syncthreads();
            buf[tid] += t;
            __syncthreads();
        }
        int excl = buf[tid] - v + carry;
        if (i < NN) { row_ptr[i] = excl; cnt_cursor[i] = excl; }
        __syncthreads();
        if (tid == 1023) carry += buf[1023];
        __syncthreads();
    }
    if (tid == 0) row_ptr[NN] = carry;
}

__global__ void fill_k(const int* __restrict__ src, const int* __restrict__ dst,
                       int* __restrict__ cursor, int* __restrict__ col) {
    int e = blockIdx.x * blockDim.x + threadIdx.x;
    if (e < NE) {
        int pos = atomicAdd(&cursor[dst[e]], 1);
        col[pos] = src[e];
    }
}

// ---------- fused gather-mean + SAGE update (+ optional final proj) ----------
// one block (128 threads) per node
template<int DIN, int DOUT, bool FINAL>
__global__ __launch_bounds__(128) void update_k(
    const int* __restrict__ row_ptr, const int* __restrict__ col,
    const float* __restrict__ h,
    const float* __restrict__ Wl, const float* __restrict__ bl,
    const float* __restrict__ Wr,
    const float* __restrict__ Wf, const float* __restrict__ bf,
    float* __restrict__ out)
{
    constexpr int R = (DIN + 31) / 32;
    __shared__ float smean[DIN];
    __shared__ float shi[DIN];
    __shared__ float sh4[FINAL ? 128 : 1];

    int i = blockIdx.x;
    int tid = threadIdx.x;
    int beg = row_ptr[i], end = row_ptr[i + 1];

    for (int k = tid; k < DIN; k += 128) {
        smean[k] = 0.0f;
        shi[k] = h[(size_t)i * DIN + k];
    }
    __syncthreads();

    // gather: 32 feature lanes x 4 edge groups
    int fx = tid & 31;
    int ey = tid >> 5;
    float acc[R];
#pragma unroll
    for (int r = 0; r < R; ++r) acc[r] = 0.0f;
    for (int e = beg + ey; e < end; e += 4) {
        const float* hs = h + (size_t)col[e] * DIN;
#pragma unroll
        for (int r = 0; r < R; ++r) {
            int k = fx + 32 * r;
            if (k < DIN) acc[r] += hs[k];
        }
    }
#pragma unroll
    for (int r = 0; r < R; ++r) {
        int k = fx + 32 * r;
        if (k < DIN) atomicAdd(&smean[k], acc[r]);
    }
    __syncthreads();

    float invdeg = 1.0f / fmaxf((float)(end - beg), 1.0f);
    float val = 0.0f;
    int j = tid;
    if (j < DOUT) {
        val = bl[j];
#pragma unroll
        for (int k = 0; k < DIN; ++k)
            val = fmaf(smean[k] * invdeg, Wl[k * DOUT + j], fmaf(shi[k], Wr[k * DOUT + j], val));
        val = fmaxf(val, 0.0f);   // ReLU
        if (!FINAL) out[(size_t)i * DOUT + j] = val;
    }
    if (FINAL) {
        // DOUT == 128 == blockDim.x
        sh4[tid] = val;
        __syncthreads();
        if (tid < 4) {
            float a = bf[tid];
#pragma unroll
            for (int k = 0; k < 128; ++k)
                a = fmaf(sh4[k], Wf[k * 4 + tid], a);
            out[(size_t)i * 4 + tid] = 1.0f / (1.0f + expf(-a));
        }
    }
}

extern "C" void kernel_launch(void* const* d_in, const int* in_sizes, int n_in,
                              void* d_out, int out_size, void* d_ws, size_t ws_size,
                              hipStream_t stream) {
    const float* x   = (const float*)d_in[0];
    const int*   ei  = (const int*)d_in[1];   // harness passes integer inputs as int32
    const int*   src = ei;                    // edge_index[0]
    const int*   dst = ei + NE;               // edge_index[1]
    const float* Wl0 = (const float*)d_in[2];
    const float* bl0 = (const float*)d_in[3];
    const float* Wr0 = (const float*)d_in[4];
    const float* Wl1 = (const float*)d_in[5];
    const float* bl1 = (const float*)d_in[6];
    const float* Wr1 = (const float*)d_in[7];
    const float* Wl2 = (const float*)d_in[8];
    const float* bl2 = (const float*)d_in[9];
    const float* Wr2 = (const float*)d_in[10];
    const float* Wl3 = (const float*)d_in[11];
    const float* bl3 = (const float*)d_in[12];
    const float* Wr3 = (const float*)d_in[13];
    const float* Wf  = (const float*)d_in[14];
    const float* bf  = (const float*)d_in[15];
    float* out = (float*)d_out;

    // workspace layout: row_ptr[NN+1] | cursor[NN] | col[NE] (ints) | bufP[NN*96] | bufQ[NN*64] (floats)
    size_t need = (size_t)(NN + 1 + NN + NE) * 4 + (size_t)NN * (96 + 64) * 4;
    if (ws_size < need) return;  // clean failure (absmax) instead of OOB core dump

    int*   row_ptr = (int*)d_ws;
    int*   cursor  = row_ptr + NN + 1;
    int*   col     = cursor + NN;
    float* bufP    = (float*)(col + NE);
    float* bufQ    = bufP + (size_t)NN * 96;

    // CSR build
    hipMemsetAsync(cursor, 0, NN * sizeof(int), stream);
    count_k<<<(NE + 255) / 256, 256, 0, stream>>>(dst, cursor);
    scan_k<<<1, 1024, 0, stream>>>(cursor, row_ptr);
    fill_k<<<(NE + 255) / 256, 256, 0, stream>>>(src, dst, cursor, col);

    // layers
    update_k<3, 32, false><<<NN, 128, 0, stream>>>(row_ptr, col, x,
        Wl0, bl0, Wr0, nullptr, nullptr, bufP);
    update_k<32, 64, false><<<NN, 128, 0, stream>>>(row_ptr, col, bufP,
        Wl1, bl1, Wr1, nullptr, nullptr, bufQ);
    update_k<64, 96, false><<<NN, 128, 0, stream>>>(row_ptr, col, bufQ,
        Wl2, bl2, Wr2, nullptr, nullptr, bufP);
    update_k<96, 128, true><<<NN, 128, 0, stream>>>(row_ptr, col, bufP,
        Wl3, bl3, Wr3, Wf, bf, out);
}

// Round 4
// 783.724 us; speedup vs baseline: 1.7008x; 1.7008x over previous
//
#include <hip/hip_runtime.h>
#include <math.h>

#define NN 100000
#define NE 1600000

__device__ inline float bsf(unsigned short u) { return __uint_as_float(((unsigned)u) << 16); }
__device__ inline unsigned short f2bs(float f) {           // RNE, matches np/hw bf16
    unsigned u = __float_as_uint(f);
    return (unsigned short)((u + 0x7fffu + ((u >> 16) & 1u)) >> 16);
}

// ---------------- CSR build ----------------
__global__ void count_k(const int* __restrict__ dst, int* __restrict__ cnt) {
    int e = blockIdx.x * blockDim.x + threadIdx.x;
    if (e < NE) atomicAdd(&cnt[dst[e]], 1);
}

__global__ void scan_k(int* __restrict__ cnt_cursor, int* __restrict__ row_ptr) {
    __shared__ int buf[1024];
    __shared__ int carry;
    int tid = threadIdx.x;
    if (tid == 0) carry = 0;
    __syncthreads();
    for (int base = 0; base < NN; base += 1024) {
        int i = base + tid;
        int v = (i < NN) ? cnt_cursor[i] : 0;
        buf[tid] = v;
        __syncthreads();
        for (int off = 1; off < 1024; off <<= 1) {
            int t = (tid >= off) ? buf[tid - off] : 0;
            __syncthreads();
            buf[tid] += t;
            __syncthreads();
        }
        int excl = buf[tid] - v + carry;
        if (i < NN) { row_ptr[i] = excl; cnt_cursor[i] = excl; }
        __syncthreads();
        if (tid == 1023) carry += buf[1023];
        __syncthreads();
    }
    if (tid == 0) row_ptr[NN] = carry;
}

__global__ void fill_k(const int* __restrict__ src, const int* __restrict__ dst,
                       int* __restrict__ cursor, int* __restrict__ col) {
    int e = blockIdx.x * blockDim.x + threadIdx.x;
    if (e < NE) {
        int pos = atomicAdd(&cursor[dst[e]], 1);
        col[pos] = src[e];
    }
}

// ---------------- layer-0 aggregation: x fp32 [N,3] -> magg bf16 [N,3] ----------------
// wave per node; fl = lane&3 (features 0..2), es = lane>>2 (16 edge slots)
__global__ __launch_bounds__(256) void agg0_k(const int* __restrict__ rp, const int* __restrict__ col,
                                              const float* __restrict__ x, unsigned short* __restrict__ magg) {
    int node = blockIdx.x * 4 + (threadIdx.x >> 6);
    int lane = threadIdx.x & 63;
    int fl = lane & 3, es = lane >> 2;
    int beg = rp[node], end = rp[node + 1];
    float acc = 0.0f;
    for (int e = beg + es; e < end; e += 16) {
        int idx = col[e];
        if (fl < 3) acc += x[(size_t)idx * 3 + fl];
    }
    acc += __shfl(acc, lane + 32);
    acc += __shfl(acc, lane + 16);
    acc += __shfl(acc, lane + 8);
    acc += __shfl(acc, lane + 4);
    if (lane < 3) {
        float inv = 1.0f / fmaxf((float)(end - beg), 1.0f);
        magg[(size_t)node * 3 + lane] = f2bs(acc * inv);
    }
}

// ---------------- generic aggregation: hb bf16 [N,DIN] -> magg bf16 [N,DIN] ----------------
// wave per node; FL = DIN/4 feature lanes (ushort4 each), EPW edge slots
template<int DIN, int FL, int EPW>
__global__ __launch_bounds__(256) void agg_k(const int* __restrict__ rp, const int* __restrict__ col,
                                             const unsigned short* __restrict__ hb,
                                             unsigned short* __restrict__ magg) {
    int node = blockIdx.x * 4 + (threadIdx.x >> 6);
    int lane = threadIdx.x & 63;
    int fl = lane % FL;
    int es = lane / FL;
    int beg = rp[node], end = rp[node + 1];
    float a0 = 0, a1 = 0, a2 = 0, a3 = 0;
    if (es < EPW) {
        for (int e = beg + es; e < end; e += EPW) {
            ushort4 v = *(const ushort4*)(hb + (size_t)col[e] * DIN + fl * 4);
            a0 += bsf(v.x); a1 += bsf(v.y); a2 += bsf(v.z); a3 += bsf(v.w);
        }
    }
    if constexpr (FL == 8) {
        a0 += __shfl(a0, lane + 32); a1 += __shfl(a1, lane + 32); a2 += __shfl(a2, lane + 32); a3 += __shfl(a3, lane + 32);
        a0 += __shfl(a0, lane + 16); a1 += __shfl(a1, lane + 16); a2 += __shfl(a2, lane + 16); a3 += __shfl(a3, lane + 16);
        a0 += __shfl(a0, lane + 8);  a1 += __shfl(a1, lane + 8);  a2 += __shfl(a2, lane + 8);  a3 += __shfl(a3, lane + 8);
    } else if constexpr (FL == 16) {
        a0 += __shfl(a0, lane + 32); a1 += __shfl(a1, lane + 32); a2 += __shfl(a2, lane + 32); a3 += __shfl(a3, lane + 32);
        a0 += __shfl(a0, lane + 16); a1 += __shfl(a1, lane + 16); a2 += __shfl(a2, lane + 16); a3 += __shfl(a3, lane + 16);
    } else { // FL == 24, EPW == 2: lanes 0..23 += lanes 24..47
        a0 += __shfl(a0, lane + 24); a1 += __shfl(a1, lane + 24); a2 += __shfl(a2, lane + 24); a3 += __shfl(a3, lane + 24);
    }
    if (lane < FL) {
        float inv = 1.0f / fmaxf((float)(end - beg), 1.0f);
        ushort4 o;
        o.x = f2bs(a0 * inv); o.y = f2bs(a1 * inv); o.z = f2bs(a2 * inv); o.w = f2bs(a3 * inv);
        *(ushort4*)(magg + (size_t)node * DIN + lane * 4) = o;
    }
}

// ---------------- tiled update: out = relu(magg@Wl + b + h@Wr) [+ fused final proj] ----------------
// 256 threads, 32 nodes/block; thread tile = 4 nodes x CT cols (CT = DOUT/32)
template<int DIN, int DOUT, int CT, bool FINAL, bool L0>
__global__ __launch_bounds__(256) void gemm_k(
    const unsigned short* __restrict__ magg, const void* __restrict__ hin,
    const float* __restrict__ Wl, const float* __restrict__ bl, const float* __restrict__ Wr,
    const float* __restrict__ Wf, const float* __restrict__ bfi,
    unsigned short* __restrict__ hout, float* __restrict__ out)
{
    __shared__ float sm[32][DIN + 1];
    __shared__ float sh[32][DIN + 1];
    __shared__ float s4[FINAL ? 32 : 1][FINAL ? 129 : 1];

    int tx = threadIdx.x;
    int base = blockIdx.x * 32;

    if (L0) {
        const float* hx = (const float*)hin;
        for (int f = tx; f < 32 * 3; f += 256) {
            int n = f / 3, k = f - n * 3;
            sm[n][k] = bsf(magg[(size_t)(base + n) * 3 + k]);
            sh[n][k] = hx[(size_t)(base + n) * 3 + k];
        }
    } else {
        const unsigned short* hb = (const unsigned short*)hin;
        constexpr int Q = DIN / 4;
        for (int f = tx; f < 32 * Q; f += 256) {
            int n = f / Q, o = f - n * Q;
            ushort4 vm = *(const ushort4*)(magg + (size_t)(base + n) * DIN + o * 4);
            ushort4 vh = *(const ushort4*)(hb   + (size_t)(base + n) * DIN + o * 4);
            sm[n][o * 4 + 0] = bsf(vm.x); sm[n][o * 4 + 1] = bsf(vm.y);
            sm[n][o * 4 + 2] = bsf(vm.z); sm[n][o * 4 + 3] = bsf(vm.w);
            sh[n][o * 4 + 0] = bsf(vh.x); sh[n][o * 4 + 1] = bsf(vh.y);
            sh[n][o * 4 + 2] = bsf(vh.z); sh[n][o * 4 + 3] = bsf(vh.w);
        }
    }
    __syncthreads();

    int ng = tx >> 5, cg = tx & 31;
    float acc[4][CT];
#pragma unroll
    for (int m = 0; m < 4; ++m)
#pragma unroll
        for (int c = 0; c < CT; ++c) acc[m][c] = bl[cg * CT + c];

#pragma unroll 4
    for (int k = 0; k < (L0 ? 3 : DIN); ++k) {
        float wl[CT], wr[CT];
#pragma unroll
        for (int c = 0; c < CT; ++c) {
            wl[c] = Wl[(size_t)k * DOUT + cg * CT + c];
            wr[c] = Wr[(size_t)k * DOUT + cg * CT + c];
        }
#pragma unroll
        for (int m = 0; m < 4; ++m) {
            float mv = sm[ng * 4 + m][k];
            float hv = sh[ng * 4 + m][k];
#pragma unroll
            for (int c = 0; c < CT; ++c)
                acc[m][c] = fmaf(mv, wl[c], fmaf(hv, wr[c], acc[m][c]));
        }
    }

#pragma unroll
    for (int m = 0; m < 4; ++m)
#pragma unroll
        for (int c = 0; c < CT; ++c) {
            float v = fmaxf(acc[m][c], 0.0f);
            if (!FINAL)
                hout[(size_t)(base + ng * 4 + m) * DOUT + cg * CT + c] = f2bs(v);
            else
                s4[ng * 4 + m][cg * CT + c] = v;
        }

    if (FINAL) {
        __syncthreads();
        if (tx < 128) {
            int n = tx >> 2, c = tx & 3;
            float a = bfi[c];
#pragma unroll 8
            for (int k = 0; k < 128; ++k)
                a = fmaf(s4[n][k], Wf[k * 4 + c], a);
            out[(size_t)(base + n) * 4 + c] = 1.0f / (1.0f + expf(-a));
        }
    }
}

extern "C" void kernel_launch(void* const* d_in, const int* in_sizes, int n_in,
                              void* d_out, int out_size, void* d_ws, size_t ws_size,
                              hipStream_t stream) {
    const float* x   = (const float*)d_in[0];
    const int*   ei  = (const int*)d_in[1];   // int32 per harness contract
    const int*   src = ei;
    const int*   dst = ei + NE;
    const float* Wl0 = (const float*)d_in[2];
    const float* bl0 = (const float*)d_in[3];
    const float* Wr0 = (const float*)d_in[4];
    const float* Wl1 = (const float*)d_in[5];
    const float* bl1 = (const float*)d_in[6];
    const float* Wr1 = (const float*)d_in[7];
    const float* Wl2 = (const float*)d_in[8];
    const float* bl2 = (const float*)d_in[9];
    const float* Wr2 = (const float*)d_in[10];
    const float* Wl3 = (const float*)d_in[11];
    const float* bl3 = (const float*)d_in[12];
    const float* Wr3 = (const float*)d_in[13];
    const float* Wf  = (const float*)d_in[14];
    const float* bf  = (const float*)d_in[15];
    float* out = (float*)d_out;

    // ws: row_ptr[NN+2] | cursor[NN] | col[NE] (int) | magg[N*96] h1[N*32] h2[N*64] h3[N*96] (bf16)
    size_t ints = (size_t)(NN + 2) + NN + NE;
    size_t need = ints * 4 + (size_t)NN * (96 + 32 + 64 + 96) * 2;
    if (ws_size < need) return;

    int* row_ptr = (int*)d_ws;
    int* cursor  = row_ptr + NN + 2;
    int* col     = cursor + NN;
    unsigned short* magg = (unsigned short*)(col + NE);  // 8B-aligned (1800002*4)
    unsigned short* h1   = magg + (size_t)NN * 96;
    unsigned short* h2   = h1 + (size_t)NN * 32;
    unsigned short* h3   = h2 + (size_t)NN * 64;

    // CSR
    hipMemsetAsync(cursor, 0, NN * sizeof(int), stream);
    count_k<<<(NE + 255) / 256, 256, 0, stream>>>(dst, cursor);
    scan_k<<<1, 1024, 0, stream>>>(cursor, row_ptr);
    fill_k<<<(NE + 255) / 256, 256, 0, stream>>>(src, dst, cursor, col);

    const int AGRID = NN / 4;     // 25000, wave per node
    const int GGRID = NN / 32;    // 3125, 32-node tiles

    // layer 0: x(3) -> h1(32)
    agg0_k<<<AGRID, 256, 0, stream>>>(row_ptr, col, x, magg);
    gemm_k<3, 32, 1, false, true><<<GGRID, 256, 0, stream>>>(
        magg, x, Wl0, bl0, Wr0, nullptr, nullptr, h1, nullptr);

    // layer 1: h1(32) -> h2(64)
    agg_k<32, 8, 8><<<AGRID, 256, 0, stream>>>(row_ptr, col, h1, magg);
    gemm_k<32, 64, 2, false, false><<<GGRID, 256, 0, stream>>>(
        magg, h1, Wl1, bl1, Wr1, nullptr, nullptr, h2, nullptr);

    // layer 2: h2(64) -> h3(96)
    agg_k<64, 16, 4><<<AGRID, 256, 0, stream>>>(row_ptr, col, h2, magg);
    gemm_k<64, 96, 3, false, false><<<GGRID, 256, 0, stream>>>(
        magg, h2, Wl2, bl2, Wr2, nullptr, nullptr, h3, nullptr);

    // layer 3 + final: h3(96) -> [128] -> out(4)
    agg_k<96, 24, 2><<<AGRID, 256, 0, stream>>>(row_ptr, col, h3, magg);
    gemm_k<96, 128, 4, true, false><<<GGRID, 256, 0, stream>>>(
        magg, h3, Wl3, bl3, Wr3, Wf, bf, nullptr, out);
}

// Round 5
// 611.850 us; speedup vs baseline: 2.1785x; 1.2809x over previous
//
#include <hip/hip_runtime.h>
#include <math.h>

#define NN 100000
#define NE 1600000
#define SCAN_B 1024
#define SCAN_NB ((NN + SCAN_B - 1) / SCAN_B)   // 98

__device__ inline float bsf(unsigned short u) { return __uint_as_float(((unsigned)u) << 16); }
__device__ inline unsigned short f2bs(float f) {           // RNE, matches np/hw bf16
    unsigned u = __float_as_uint(f);
    return (unsigned short)((u + 0x7fffu + ((u >> 16) & 1u)) >> 16);
}

// ---------------- CSR build ----------------
__global__ void count_k(const int* __restrict__ dst, int* __restrict__ cnt) {
    int e = blockIdx.x * blockDim.x + threadIdx.x;
    if (e < NE) atomicAdd(&cnt[dst[e]], 1);
}

// pass 1: per-block exclusive scan of cnt -> row_ptr (local), block totals -> bsum
__global__ __launch_bounds__(SCAN_B) void scan1_k(const int* __restrict__ cnt,
                                                  int* __restrict__ row_ptr,
                                                  int* __restrict__ bsum) {
    __shared__ int wsum[16];
    int tid = threadIdx.x;
    int i = blockIdx.x * SCAN_B + tid;
    int v = (i < NN) ? cnt[i] : 0;
    int lane = tid & 63, wid = tid >> 6;
    int s = v;
#pragma unroll
    for (int off = 1; off < 64; off <<= 1) {
        int t = __shfl_up(s, off);
        if (lane >= off) s += t;
    }
    if (lane == 63) wsum[wid] = s;
    __syncthreads();
    if (wid == 0) {
        int w = (lane < 16) ? wsum[lane] : 0;
#pragma unroll
        for (int off = 1; off < 16; off <<= 1) {
            int t = __shfl_up(w, off);
            if (lane >= off) w += t;
        }
        if (lane < 16) wsum[lane] = w;
    }
    __syncthreads();
    int incl = s + (wid > 0 ? wsum[wid - 1] : 0);
    if (i < NN) row_ptr[i] = incl - v;          // local exclusive
    if (tid == SCAN_B - 1) bsum[blockIdx.x] = wsum[15];  // block total
}

// pass 2: single wave scans block sums (exclusive, in place), total -> row_ptr[NN]
__global__ void scan2_k(int* __restrict__ bsum, int* __restrict__ row_ptr) {
    int lane = threadIdx.x;      // 0..63, SCAN_NB=98 needs 2 rounds
    __shared__ int carry;
    if (lane == 0) carry = 0;
    __syncthreads();
    for (int base = 0; base < SCAN_NB; base += 64) {
        int idx = base + lane;
        int v = (idx < SCAN_NB) ? bsum[idx] : 0;
        int s = v;
#pragma unroll
        for (int off = 1; off < 64; off <<= 1) {
            int t = __shfl_up(s, off);
            if (lane >= off) s += t;
        }
        if (idx < SCAN_NB) bsum[idx] = s - v + carry;  // exclusive
        __syncthreads();
        if (lane == 63) carry += s;
        __syncthreads();
    }
    if (lane == 0) row_ptr[NN] = carry;
}

// pass 3: add block base; mirror into cursor
__global__ __launch_bounds__(SCAN_B) void scan3_k(int* __restrict__ row_ptr,
                                                  const int* __restrict__ bsum,
                                                  int* __restrict__ cursor) {
    int i = blockIdx.x * SCAN_B + threadIdx.x;
    if (i < NN) {
        int r = row_ptr[i] + bsum[blockIdx.x];
        row_ptr[i] = r;
        cursor[i] = r;
    }
}

__global__ void fill_k(const int* __restrict__ src, const int* __restrict__ dst,
                       int* __restrict__ cursor, int* __restrict__ col) {
    int e = blockIdx.x * blockDim.x + threadIdx.x;
    if (e < NE) {
        int pos = atomicAdd(&cursor[dst[e]], 1);
        col[pos] = src[e];
    }
}

// ---------------- layer-0 aggregation: x fp32 [N,3] -> magg bf16 [N,3] ----------------
__global__ __launch_bounds__(256) void agg0_k(const int* __restrict__ rp, const int* __restrict__ col,
                                              const float* __restrict__ x, unsigned short* __restrict__ magg) {
    int node = blockIdx.x * 4 + (threadIdx.x >> 6);
    int lane = threadIdx.x & 63;
    int fl = lane & 3, es = lane >> 2;
    int beg = rp[node], end = rp[node + 1];
    float acc = 0.0f;
    for (int e = beg + es; e < end; e += 16) {
        int idx = col[e];
        if (fl < 3) acc += x[(size_t)idx * 3 + fl];
    }
    acc += __shfl(acc, lane + 32);
    acc += __shfl(acc, lane + 16);
    acc += __shfl(acc, lane + 8);
    acc += __shfl(acc, lane + 4);
    if (lane < 3) {
        float inv = 1.0f / fmaxf((float)(end - beg), 1.0f);
        magg[(size_t)node * 3 + lane] = f2bs(acc * inv);
    }
}

// ---------------- generic aggregation: hb bf16 [N,DIN] -> magg bf16 [N,DIN] ----------------
template<int DIN, int FL, int EPW>
__global__ __launch_bounds__(256) void agg_k(const int* __restrict__ rp, const int* __restrict__ col,
                                             const unsigned short* __restrict__ hb,
                                             unsigned short* __restrict__ magg) {
    int node = blockIdx.x * 4 + (threadIdx.x >> 6);
    int lane = threadIdx.x & 63;
    int fl = lane % FL;
    int es = lane / FL;
    int beg = rp[node], end = rp[node + 1];
    float a0 = 0, a1 = 0, a2 = 0, a3 = 0;
    if (es < EPW) {
        for (int e = beg + es; e < end; e += EPW) {
            ushort4 v = *(const ushort4*)(hb + (size_t)col[e] * DIN + fl * 4);
            a0 += bsf(v.x); a1 += bsf(v.y); a2 += bsf(v.z); a3 += bsf(v.w);
        }
    }
    if constexpr (FL == 8) {
        a0 += __shfl(a0, lane + 32); a1 += __shfl(a1, lane + 32); a2 += __shfl(a2, lane + 32); a3 += __shfl(a3, lane + 32);
        a0 += __shfl(a0, lane + 16); a1 += __shfl(a1, lane + 16); a2 += __shfl(a2, lane + 16); a3 += __shfl(a3, lane + 16);
        a0 += __shfl(a0, lane + 8);  a1 += __shfl(a1, lane + 8);  a2 += __shfl(a2, lane + 8);  a3 += __shfl(a3, lane + 8);
    } else if constexpr (FL == 16) {
        a0 += __shfl(a0, lane + 32); a1 += __shfl(a1, lane + 32); a2 += __shfl(a2, lane + 32); a3 += __shfl(a3, lane + 32);
        a0 += __shfl(a0, lane + 16); a1 += __shfl(a1, lane + 16); a2 += __shfl(a2, lane + 16); a3 += __shfl(a3, lane + 16);
    } else { // FL == 24, EPW == 2
        a0 += __shfl(a0, lane + 24); a1 += __shfl(a1, lane + 24); a2 += __shfl(a2, lane + 24); a3 += __shfl(a3, lane + 24);
    }
    if (lane < FL) {
        float inv = 1.0f / fmaxf((float)(end - beg), 1.0f);
        ushort4 o;
        o.x = f2bs(a0 * inv); o.y = f2bs(a1 * inv); o.z = f2bs(a2 * inv); o.w = f2bs(a3 * inv);
        *(ushort4*)(magg + (size_t)node * DIN + lane * 4) = o;
    }
}

// ---------------- tiled update ----------------
template<int DIN, int DOUT, int CT, bool FINAL, bool L0>
__global__ __launch_bounds__(256) void gemm_k(
    const unsigned short* __restrict__ magg, const void* __restrict__ hin,
    const float* __restrict__ Wl, const float* __restrict__ bl, const float* __restrict__ Wr,
    const float* __restrict__ Wf, const float* __restrict__ bfi,
    unsigned short* __restrict__ hout, float* __restrict__ out)
{
    __shared__ float sm[32][DIN + 1];
    __shared__ float sh[32][DIN + 1];
    __shared__ float s4[FINAL ? 32 : 1][FINAL ? 129 : 1];

    int tx = threadIdx.x;
    int base = blockIdx.x * 32;

    if (L0) {
        const float* hx = (const float*)hin;
        for (int f = tx; f < 32 * 3; f += 256) {
            int n = f / 3, k = f - n * 3;
            sm[n][k] = bsf(magg[(size_t)(base + n) * 3 + k]);
            sh[n][k] = hx[(size_t)(base + n) * 3 + k];
        }
    } else {
        const unsigned short* hb = (const unsigned short*)hin;
        constexpr int Q = DIN / 4;
        for (int f = tx; f < 32 * Q; f += 256) {
            int n = f / Q, o = f - n * Q;
            ushort4 vm = *(const ushort4*)(magg + (size_t)(base + n) * DIN + o * 4);
            ushort4 vh = *(const ushort4*)(hb   + (size_t)(base + n) * DIN + o * 4);
            sm[n][o * 4 + 0] = bsf(vm.x); sm[n][o * 4 + 1] = bsf(vm.y);
            sm[n][o * 4 + 2] = bsf(vm.z); sm[n][o * 4 + 3] = bsf(vm.w);
            sh[n][o * 4 + 0] = bsf(vh.x); sh[n][o * 4 + 1] = bsf(vh.y);
            sh[n][o * 4 + 2] = bsf(vh.z); sh[n][o * 4 + 3] = bsf(vh.w);
        }
    }
    __syncthreads();

    int ng = tx >> 5, cg = tx & 31;
    float acc[4][CT];
#pragma unroll
    for (int m = 0; m < 4; ++m)
#pragma unroll
        for (int c = 0; c < CT; ++c) acc[m][c] = bl[cg * CT + c];

#pragma unroll 4
    for (int k = 0; k < (L0 ? 3 : DIN); ++k) {
        float wl[CT], wr[CT];
#pragma unroll
        for (int c = 0; c < CT; ++c) {
            wl[c] = Wl[(size_t)k * DOUT + cg * CT + c];
            wr[c] = Wr[(size_t)k * DOUT + cg * CT + c];
        }
#pragma unroll
        for (int m = 0; m < 4; ++m) {
            float mv = sm[ng * 4 + m][k];
            float hv = sh[ng * 4 + m][k];
#pragma unroll
            for (int c = 0; c < CT; ++c)
                acc[m][c] = fmaf(mv, wl[c], fmaf(hv, wr[c], acc[m][c]));
        }
    }

#pragma unroll
    for (int m = 0; m < 4; ++m)
#pragma unroll
        for (int c = 0; c < CT; ++c) {
            float v = fmaxf(acc[m][c], 0.0f);
            if (!FINAL)
                hout[(size_t)(base + ng * 4 + m) * DOUT + cg * CT + c] = f2bs(v);
            else
                s4[ng * 4 + m][cg * CT + c] = v;
        }

    if (FINAL) {
        __syncthreads();
        if (tx < 128) {
            int n = tx >> 2, c = tx & 3;
            float a = bfi[c];
#pragma unroll 8
            for (int k = 0; k < 128; ++k)
                a = fmaf(s4[n][k], Wf[k * 4 + c], a);
            out[(size_t)(base + n) * 4 + c] = 1.0f / (1.0f + expf(-a));
        }
    }
}

extern "C" void kernel_launch(void* const* d_in, const int* in_sizes, int n_in,
                              void* d_out, int out_size, void* d_ws, size_t ws_size,
                              hipStream_t stream) {
    const float* x   = (const float*)d_in[0];
    const int*   ei  = (const int*)d_in[1];
    const int*   src = ei;
    const int*   dst = ei + NE;
    const float* Wl0 = (const float*)d_in[2];
    const float* bl0 = (const float*)d_in[3];
    const float* Wr0 = (const float*)d_in[4];
    const float* Wl1 = (const float*)d_in[5];
    const float* bl1 = (const float*)d_in[6];
    const float* Wr1 = (const float*)d_in[7];
    const float* Wl2 = (const float*)d_in[8];
    const float* bl2 = (const float*)d_in[9];
    const float* Wr2 = (const float*)d_in[10];
    const float* Wl3 = (const float*)d_in[11];
    const float* bl3 = (const float*)d_in[12];
    const float* Wr3 = (const float*)d_in[13];
    const float* Wf  = (const float*)d_in[14];
    const float* bf  = (const float*)d_in[15];
    float* out = (float*)d_out;

    // ws: row_ptr[NN+2] | cursor[NN] | bsum[128] | col[NE] (int) | magg[N*96] h1[N*32] h2[N*64] h3[N*96] (bf16)
    size_t ints = (size_t)(NN + 2) + NN + 128 + NE;
    size_t need = ints * 4 + (size_t)NN * (96 + 32 + 64 + 96) * 2;
    if (ws_size < need) return;

    int* row_ptr = (int*)d_ws;
    int* cursor  = row_ptr + NN + 2;
    int* bsum    = cursor + NN;
    int* col     = bsum + 128;
    unsigned short* magg = (unsigned short*)(col + NE);
    unsigned short* h1   = magg + (size_t)NN * 96;
    unsigned short* h2   = h1 + (size_t)NN * 32;
    unsigned short* h3   = h2 + (size_t)NN * 64;

    // CSR build (hierarchical scan)
    hipMemsetAsync(cursor, 0, NN * sizeof(int), stream);
    count_k<<<(NE + 255) / 256, 256, 0, stream>>>(dst, cursor);
    scan1_k<<<SCAN_NB, SCAN_B, 0, stream>>>(cursor, row_ptr, bsum);
    scan2_k<<<1, 64, 0, stream>>>(bsum, row_ptr);
    scan3_k<<<SCAN_NB, SCAN_B, 0, stream>>>(row_ptr, bsum, cursor);
    fill_k<<<(NE + 255) / 256, 256, 0, stream>>>(src, dst, cursor, col);

    const int AGRID = NN / 4;
    const int GGRID = NN / 32;

    // layer 0: x(3) -> h1(32)
    agg0_k<<<AGRID, 256, 0, stream>>>(row_ptr, col, x, magg);
    gemm_k<3, 32, 1, false, true><<<GGRID, 256, 0, stream>>>(
        magg, x, Wl0, bl0, Wr0, nullptr, nullptr, h1, nullptr);

    // layer 1: h1(32) -> h2(64)
    agg_k<32, 8, 8><<<AGRID, 256, 0, stream>>>(row_ptr, col, h1, magg);
    gemm_k<32, 64, 2, false, false><<<GGRID, 256, 0, stream>>>(
        magg, h1, Wl1, bl1, Wr1, nullptr, nullptr, h2, nullptr);

    // layer 2: h2(64) -> h3(96)
    agg_k<64, 16, 4><<<AGRID, 256, 0, stream>>>(row_ptr, col, h2, magg);
    gemm_k<64, 96, 3, false, false><<<GGRID, 256, 0, stream>>>(
        magg, h2, Wl2, bl2, Wr2, nullptr, nullptr, h3, nullptr);

    // layer 3 + final
    agg_k<96, 24, 2><<<AGRID, 256, 0, stream>>>(row_ptr, col, h3, magg);
    gemm_k<96, 128, 4, true, false><<<GGRID, 256, 0, stream>>>(
        magg, h3, Wl3, bl3, Wr3, Wf, bf, nullptr, out);
}